// Round 20
// baseline (275.973 us; speedup 1.0000x reference)
//
#include <hip/hip_runtime.h>
#include <math.h>

#define N_NODES 50000
#define PAD_ROWS 50176                 // 392 * 128
#define DUAL_BLOCKS 196                // each block: tiles b and b+196
#define HALF_OFF (196 * 128)           // 25088 row offset of second half
#define E_RAW   400000
#define E_TOT   (E_RAW + N_NODES)      // 450000 incl. self loops
#define NEG_SLOPE 0.2f

typedef __bf16 bf16_t;
typedef bf16_t bf16x8 __attribute__((ext_vector_type(8)));
typedef bf16_t bf16x4 __attribute__((ext_vector_type(4)));
typedef float  f32x4  __attribute__((ext_vector_type(4)));
typedef unsigned int u32x4 __attribute__((ext_vector_type(4)));

__device__ __forceinline__ void gll16(const void* g, void* l) {
    __builtin_amdgcn_global_load_lds(
        (const __attribute__((address_space(1))) void*)g,
        (__attribute__((address_space(3))) void*)l, 16, 0, 0);
}

// nontemporal 16B load of a bf16 row fragment (streaming: h rows have ~no
// L2 reuse across a random graph; keep L2 for srcs/As/offs instead)
__device__ __forceinline__ bf16x8 ldnt_row(const bf16_t* p) {
    u32x4 v = __builtin_nontemporal_load((const u32x4*)p);
    union { u32x4 u; bf16x8 b; } cvt;
    cvt.u = v;
    return cvt.b;
}

// ---------------- CSR build ----------------

__global__ void k_hist(const int* __restrict__ ei, int* __restrict__ cnt) {
    int e = blockIdx.x * 256 + threadIdx.x;
    if (e >= E_TOT) return;
    int dst = (e < E_RAW) ? ei[E_RAW + e] : (e - E_RAW);
    atomicAdd(&cnt[dst], 1);
}

__global__ void k_scan1(const int* __restrict__ cnt, int* __restrict__ offs,
                        int* __restrict__ bsum) {
    __shared__ int s[256];
    int i = blockIdx.x * 256 + threadIdx.x;
    int v = (i < N_NODES) ? cnt[i] : 0;
    s[threadIdx.x] = v;
    __syncthreads();
    for (int d = 1; d < 256; d <<= 1) {
        int t = (threadIdx.x >= d) ? s[threadIdx.x - d] : 0;
        __syncthreads();
        s[threadIdx.x] += t;
        __syncthreads();
    }
    if (i < N_NODES) offs[i] = s[threadIdx.x] - v;   // exclusive (intra-block)
    if (threadIdx.x == 255) bsum[blockIdx.x] = s[255];
}

// scan2+scan3 fused (R18-verified)
__global__ void k_scan23(int* __restrict__ offs, const int* __restrict__ bsum,
                         int nb) {
    __shared__ int s[256];
    int v = (threadIdx.x < nb) ? bsum[threadIdx.x] : 0;
    s[threadIdx.x] = v;
    __syncthreads();
    for (int d = 1; d < 256; d <<= 1) {
        int t = (threadIdx.x >= d) ? s[threadIdx.x - d] : 0;
        __syncthreads();
        s[threadIdx.x] += t;
        __syncthreads();
    }
    int add = (blockIdx.x == 0) ? 0 : s[blockIdx.x - 1];
    int i = blockIdx.x * 256 + threadIdx.x;
    if (i < N_NODES) offs[i] += add;
}

__global__ void k_scatter(const int* __restrict__ ei, const int* __restrict__ offs,
                          int* __restrict__ cursor, int* __restrict__ srcs) {
    int e = blockIdx.x * 256 + threadIdx.x;
    if (e < 64) srcs[E_TOT + e] = 0;                // pad (overrun-safe reads)
    if (e >= E_TOT) return;
    int src, dst;
    if (e < E_RAW) { src = ei[e]; dst = ei[E_RAW + e]; }
    else           { src = dst = e - E_RAW; }
    int pos = offs[dst] + atomicAdd(&cursor[dst], 1);
    srcs[pos] = src;
}

// ---------------- W splits + cnts/cursor zeroing (runs FIRST) --------------

__global__ void k_split_all(const float* __restrict__ W0, const float* __restrict__ W1,
                            const float* __restrict__ W2,
                            bf16_t* __restrict__ T0h, bf16_t* __restrict__ T0l,
                            bf16_t* __restrict__ T1h, bf16_t* __restrict__ T1l,
                            bf16_t* __restrict__ T2h, bf16_t* __restrict__ T2l,
                            int* __restrict__ cnts, int* __restrict__ cursor) {
    int idx = blockIdx.x * 256 + threadIdx.x;    // 139264 total
    if (idx < N_NODES) { cnts[idx] = 0; cursor[idx] = 0; }
    float v; bf16_t *ph, *pl; int o;
    if (idx < 65536) {
        int k = idx >> 8, n = idx & 255;
        v = W0[idx]; ph = T0h; pl = T0l; o = n * 256 + k;
    } else if (idx < 131072) {
        int i = idx - 65536;
        int k = i >> 8, n = i & 255;
        v = W1[i]; ph = T1h; pl = T1l; o = n * 256 + k;
    } else if (idx < 139264) {
        int i = idx - 131072;                    // < 8192
        int k = i >> 5, n = i & 31;
        v = W2[i]; ph = T2h; pl = T2l; o = n * 256 + k;
    } else return;
    bf16_t h = (bf16_t)v;
    ph[o] = h;
    pl[o] = (bf16_t)(v - (float)h);
}

// ---------------- MFMA GEMM: dual independent tiles per block --------------
// (R13-verified)

template<bool A_FP32>
__global__ __launch_bounds__(512) void k_gemm256_dual(
        const float* __restrict__ Af, const bf16_t* __restrict__ Ab,
        const bf16_t* __restrict__ Bth,
        const float* __restrict__ a_s, const float* __restrict__ a_d,
        bf16_t* __restrict__ Hb, float* __restrict__ As, float* __restrict__ Ad) {
    __shared__ __align__(16) bf16_t Bs[16][8][512];   // 131072 B

    const int tid  = threadIdx.x;
    const int lane = tid & 63;
    const int w    = tid >> 6;       // 0..7: 16-row band
    const int r16  = lane & 15;
    const int kg   = lane >> 4;      // 0..3

    #pragma unroll
    for (int i = 0; i < 16; ++i) {
        int op   = w * 16 + i;       // 0..127
        int nsub = op >> 3;          // 0..15
        int kk   = op & 7;           // 0..7
        gll16(&Bth[(nsub * 16 + r16) * 256 + kk * 32 + kg * 8], &Bs[nsub][kk][0]);
    }

    const int row0  = blockIdx.x * 128 + w * 16 + r16;
    const int row1  = row0 + HALF_OFF;
    const int rowc0 = min(row0, N_NODES - 1);
    const int rowc1 = min(row1, N_NODES - 1);
    const bool ok0  = row0 < N_NODES;
    const bool ok1  = row1 < N_NODES;

    bf16x8 x0[8], x1[8];
    if constexpr (A_FP32) {
        const float* a0 = Af + rowc0 * 256 + kg * 8;
        const float* a1 = Af + rowc1 * 256 + kg * 8;
        #pragma unroll
        for (int kk = 0; kk < 8; ++kk) {
            float4 v0 = *(const float4*)(a0 + kk * 32);
            float4 v1 = *(const float4*)(a0 + kk * 32 + 4);
            float4 u0 = *(const float4*)(a1 + kk * 32);
            float4 u1 = *(const float4*)(a1 + kk * 32 + 4);
            x0[kk] = bf16x8{(bf16_t)v0.x, (bf16_t)v0.y, (bf16_t)v0.z, (bf16_t)v0.w,
                            (bf16_t)v1.x, (bf16_t)v1.y, (bf16_t)v1.z, (bf16_t)v1.w};
            x1[kk] = bf16x8{(bf16_t)u0.x, (bf16_t)u0.y, (bf16_t)u0.z, (bf16_t)u0.w,
                            (bf16_t)u1.x, (bf16_t)u1.y, (bf16_t)u1.z, (bf16_t)u1.w};
        }
    } else {
        const bf16_t* a0 = Ab + rowc0 * 256 + kg * 8;
        const bf16_t* a1 = Ab + rowc1 * 256 + kg * 8;
        #pragma unroll
        for (int kk = 0; kk < 8; ++kk) {
            x0[kk] = *(const bf16x8*)(a0 + kk * 32);
            x1[kk] = *(const bf16x8*)(a1 + kk * 32);
        }
    }
    __syncthreads();   // B resident

    f32x4 acc0[16] = {}, acc1[16] = {};
    #pragma unroll
    for (int kk = 0; kk < 8; ++kk) {
        #pragma unroll
        for (int n = 0; n < 16; ++n) {
            bf16x8 wf = *(const bf16x8*)&Bs[n][kk][lane * 8];
            acc0[n] = __builtin_amdgcn_mfma_f32_16x16x32_bf16(wf, x0[kk], acc0[n], 0, 0, 0);
            acc1[n] = __builtin_amdgcn_mfma_f32_16x16x32_bf16(wf, x1[kk], acc1[n], 0, 0, 0);
        }
    }

    {
        float ss = 0.f, sd = 0.f;
        #pragma unroll
        for (int n = 0; n < 16; ++n) {
            f32x4 v = acc0[n];
            if (ok0) {
                bf16x4 st = {(bf16_t)v[0], (bf16_t)v[1], (bf16_t)v[2], (bf16_t)v[3]};
                *(bf16x4*)&Hb[row0 * 256 + n * 16 + kg * 4] = st;
            }
            float4 a4 = *(const float4*)&a_s[n * 16 + kg * 4];
            float4 d4 = *(const float4*)&a_d[n * 16 + kg * 4];
            ss += v[0] * a4.x + v[1] * a4.y + v[2] * a4.z + v[3] * a4.w;
            sd += v[0] * d4.x + v[1] * d4.y + v[2] * d4.z + v[3] * d4.w;
        }
        ss += __shfl_xor(ss, 16); ss += __shfl_xor(ss, 32);
        sd += __shfl_xor(sd, 16); sd += __shfl_xor(sd, 32);
        if (ok0 && kg == 0) { As[row0] = ss; Ad[row0] = sd; }
    }
    {
        float ss = 0.f, sd = 0.f;
        #pragma unroll
        for (int n = 0; n < 16; ++n) {
            f32x4 v = acc1[n];
            if (ok1) {
                bf16x4 st = {(bf16_t)v[0], (bf16_t)v[1], (bf16_t)v[2], (bf16_t)v[3]};
                *(bf16x4*)&Hb[row1 * 256 + n * 16 + kg * 4] = st;
            }
            float4 a4 = *(const float4*)&a_s[n * 16 + kg * 4];
            float4 d4 = *(const float4*)&a_d[n * 16 + kg * 4];
            ss += v[0] * a4.x + v[1] * a4.y + v[2] * a4.z + v[3] * a4.w;
            sd += v[0] * d4.x + v[1] * d4.y + v[2] * d4.z + v[3] * d4.w;
        }
        ss += __shfl_xor(ss, 16); ss += __shfl_xor(ss, 32);
        sd += __shfl_xor(sd, 16); sd += __shfl_xor(sd, 32);
        if (ok1 && kg == 0) { As[row1] = ss; Ad[row1] = sd; }
    }
}

// ---------------- GEMM 32-out (layer 2), swapped operands ------------------

__global__ __launch_bounds__(256) void k_gemm32_mfma(
        const bf16_t* __restrict__ Ab,
        const bf16_t* __restrict__ Bth, const bf16_t* __restrict__ Btl,
        const float* __restrict__ a_s, const float* __restrict__ a_d,
        float* __restrict__ Hc, float* __restrict__ As, float* __restrict__ Ad) {
    const int tid  = threadIdx.x;
    const int lane = tid & 63;
    const int wv   = tid >> 6;
    const int r16  = lane & 15;
    const int kg   = lane >> 4;
    const int rowg = blockIdx.x * 256 + wv * 64;

    int aoff[4], boff[2];
    #pragma unroll
    for (int m = 0; m < 4; ++m) {
        int row = rowg + m * 16 + r16;
        if (row >= N_NODES) row = N_NODES - 1;
        aoff[m] = row * 256 + kg * 8;
    }
    #pragma unroll
    for (int n = 0; n < 2; ++n)
        boff[n] = (n * 16 + r16) * 256 + kg * 8;

    f32x4 accT[2][4] = {};   // [n][m]

    #pragma unroll
    for (int kk = 0; kk < 8; ++kk) {
        const int k0 = kk * 32;
        bf16x8 ah[4], bh[2], bl[2];
        #pragma unroll
        for (int m = 0; m < 4; ++m)
            ah[m] = *(const bf16x8*)(Ab + aoff[m] + k0);
        #pragma unroll
        for (int n = 0; n < 2; ++n) {
            bh[n] = *(const bf16x8*)(Bth + boff[n] + k0);
            bl[n] = *(const bf16x8*)(Btl + boff[n] + k0);
        }
        #pragma unroll
        for (int n = 0; n < 2; ++n) {
            #pragma unroll
            for (int m = 0; m < 4; ++m) {
                accT[n][m] = __builtin_amdgcn_mfma_f32_16x16x32_bf16(bh[n], ah[m], accT[n][m], 0, 0, 0);
                accT[n][m] = __builtin_amdgcn_mfma_f32_16x16x32_bf16(bl[n], ah[m], accT[n][m], 0, 0, 0);
            }
        }
    }

    float4 as4[2], ad4[2];
    #pragma unroll
    for (int n = 0; n < 2; ++n) {
        as4[n] = *(const float4*)&a_s[n * 16 + kg * 4];
        ad4[n] = *(const float4*)&a_d[n * 16 + kg * 4];
    }
    #pragma unroll
    for (int m = 0; m < 4; ++m) {
        int row = rowg + m * 16 + r16;
        bool ok = row < N_NODES;
        float ss = 0.f, sd = 0.f;
        #pragma unroll
        for (int n = 0; n < 2; ++n) {
            f32x4 v = accT[n][m];
            if (ok) {
                float4 st = {v[0], v[1], v[2], v[3]};
                *(float4*)&Hc[row * 32 + n * 16 + kg * 4] = st;
            }
            ss += v[0] * as4[n].x + v[1] * as4[n].y + v[2] * as4[n].z + v[3] * as4[n].w;
            sd += v[0] * ad4[n].x + v[1] * ad4[n].y + v[2] * ad4[n].z + v[3] * ad4[n].w;
        }
        ss += __shfl_xor(ss, 16); ss += __shfl_xor(ss, 32);
        sd += __shfl_xor(sd, 16); sd += __shfl_xor(sd, 32);
        if (ok && kg == 0) { As[row] = ss; Ad[row] = sd; }
    }
}

// ---------------- Fused softmax+gather: dual node, 8-deep MLP --------------
// Half-wave handles nodes n0=2*hw, n1=n0+1; edge loop unrolled x8 so up to
// 16 independent h-loads are in flight (latency x concurrency is the gather
// limiter: per-XCD L2 reuse ~1.1x on a random graph). h loads nontemporal
// (streaming) to keep srcs/As/offs hot in L2. Max-free softmax (R18).

#define UN 8

__global__ __launch_bounds__(256) void k_gather256_f(
        const bf16_t* __restrict__ Hb,
        const float* __restrict__ As, const float* __restrict__ Ad,
        const int* __restrict__ offs, const int* __restrict__ cnts,
        const int* __restrict__ srcs,
        const float* __restrict__ bias, bf16_t* __restrict__ Hout) {
    const int gl = threadIdx.x & 31;
    const int hw = blockIdx.x * 8 + (threadIdx.x >> 5);
    const int n0 = hw * 2, n1 = n0 + 1;
    if (n0 >= N_NODES) return;
    const bool has1 = n1 < N_NODES;
    const int st0 = offs[n0], c0n = cnts[n0];
    const int st1 = has1 ? offs[n1] : st0;
    const int c1n = has1 ? cnts[n1] : 0;
    const float ad0 = Ad[n0];
    const float ad1 = has1 ? Ad[n1] : 0.f;
    const int c0 = gl * 8;

    float acc0[8] = {}, acc1[8] = {};
    float den0 = 0.f, den1 = 0.f;
    const int jmax = max(c0n, c1n);
    for (int j = 0; j < jmax; j += UN) {
        int s0[UN], s1[UN];
        #pragma unroll
        for (int k = 0; k < UN; ++k) {
            s0[k] = srcs[st0 + j + k];   // pad/overrun-safe (masked below)
            s1[k] = srcs[st1 + j + k];
        }
        #pragma unroll
        for (int k = 0; k < UN; ++k) {
            if (j + k < c0n) {
                int s = s0[k];
                float e = As[s] + ad0;
                e = e > 0.f ? e : NEG_SLOPE * e;
                float p = __expf(e);
                den0 += p;
                bf16x8 hv = ldnt_row(&Hb[s * 256 + c0]);
                #pragma unroll
                for (int q = 0; q < 8; ++q) acc0[q] += p * (float)hv[q];
            }
            if (j + k < c1n) {
                int s = s1[k];
                float e = As[s] + ad1;
                e = e > 0.f ? e : NEG_SLOPE * e;
                float p = __expf(e);
                den1 += p;
                bf16x8 hv = ldnt_row(&Hb[s * 256 + c0]);
                #pragma unroll
                for (int q = 0; q < 8; ++q) acc1[q] += p * (float)hv[q];
            }
        }
    }

    float4 b0 = *(const float4*)&bias[c0];
    float4 b1 = *(const float4*)&bias[c0 + 4];
    float bb[8] = {b0.x, b0.y, b0.z, b0.w, b1.x, b1.y, b1.z, b1.w};
    {
        const float iv = 1.f / den0;
        bf16x8 st;
        #pragma unroll
        for (int q = 0; q < 8; ++q) {
            float v = acc0[q] * iv + bb[q];
            v = v / (1.f + __expf(-v));
            st[q] = (bf16_t)v;
        }
        *(bf16x8*)&Hout[n0 * 256 + c0] = st;
    }
    if (has1) {
        const float iv = 1.f / den1;
        bf16x8 st;
        #pragma unroll
        for (int q = 0; q < 8; ++q) {
            float v = acc1[q] * iv + bb[q];
            v = v / (1.f + __expf(-v));
            st[q] = (bf16_t)v;
        }
        *(bf16x8*)&Hout[n1 * 256 + c0] = st;
    }
}

// ---------------- Fused final gather (max-free, 8-deep) + log_softmax ------

__global__ __launch_bounds__(256) void k_gather_final_f(
        const float* __restrict__ Hc,   // [N][32]
        const float* __restrict__ As, const float* __restrict__ Ad,
        const int* __restrict__ offs, const int* __restrict__ cnts,
        const int* __restrict__ srcs,
        const float* __restrict__ bias, float* __restrict__ out) {
    const int gl   = threadIdx.x & 31;
    const int node = blockIdx.x * 8 + (threadIdx.x >> 5);
    if (node >= N_NODES) return;
    const int start = offs[node];
    const int cnt   = cnts[node];
    const float ad  = Ad[node];

    float acc = 0.f, denom = 0.f;
    for (int j = 0; j < cnt; j += UN) {
        int s4[UN];
        #pragma unroll
        for (int k = 0; k < UN; ++k) s4[k] = srcs[start + j + k];
        #pragma unroll
        for (int k = 0; k < UN; ++k) {
            if (j + k < cnt) {
                int s = s4[k];
                float e = As[s] + ad;
                e = e > 0.f ? e : NEG_SLOPE * e;
                float p = __expf(e);
                denom += p;
                acc += p * __builtin_nontemporal_load(&Hc[s * 32 + gl]);
            }
        }
    }

    float v = acc / denom + bias[gl];
    float mm = v;
    #pragma unroll
    for (int o = 16; o; o >>= 1) mm = fmaxf(mm, __shfl_xor(mm, o));
    float ex = __expf(v - mm), sum = ex;
    #pragma unroll
    for (int o = 16; o; o >>= 1) sum += __shfl_xor(sum, o);
    out[node * 32 + gl] = v - mm - __logf(sum);
}

// ---------------- launch ----------------

extern "C" void kernel_launch(void* const* d_in, const int* in_sizes, int n_in,
                              void* d_out, int out_size, void* d_ws, size_t ws_size,
                              hipStream_t stream) {
    const float* x   = (const float*)d_in[0];
    const int*   ei  = (const int*)  d_in[1];
    const float* W0  = (const float*)d_in[2];
    const float* as0 = (const float*)d_in[3];
    const float* ad0 = (const float*)d_in[4];
    const float* b0  = (const float*)d_in[5];
    const float* W1  = (const float*)d_in[6];
    const float* as1 = (const float*)d_in[7];
    const float* ad1 = (const float*)d_in[8];
    const float* b1  = (const float*)d_in[9];
    const float* W2  = (const float*)d_in[10];
    const float* as2 = (const float*)d_in[11];
    const float* ad2 = (const float*)d_in[12];
    const float* b2  = (const float*)d_in[13];
    float* out = (float*)d_out;

    char* ws = (char*)d_ws;
    bf16_t* hA_b  = (bf16_t*)(ws + 0);           // 25,690,112
    bf16_t* hB_b  = (bf16_t*)(ws + 25690112);    // 25,690,112
    float*  hC    = (float*) (ws + 51380224);    //  6,400,000
    float*  As    = (float*) (ws + 57780224);    //    200,000
    float*  Ad    = (float*) (ws + 57980224);    //    200,000
    int*    cnts  = (int*)   (ws + 58180224);    //    200,000
    int*    cursor= (int*)   (ws + 58380224);    //    200,000
    int*    offs  = (int*)   (ws + 58580224);    //    200,000
    int*    srcs  = (int*)   (ws + 58780224);    //  1,800,256 (E_TOT+64)
    int*    bsum  = (int*)   (ws + 60580480);    //      1,024
    bf16_t* Wth0  = (bf16_t*)(ws + 60581504);    //    131,072
    bf16_t* Wtl0  = (bf16_t*)(ws + 60712576);    //    131,072
    bf16_t* Wth1  = (bf16_t*)(ws + 60843648);    //    131,072
    bf16_t* Wtl1  = (bf16_t*)(ws + 60974720);    //    131,072
    bf16_t* Wth2  = (bf16_t*)(ws + 61105792);    //     16,384
    bf16_t* Wtl2  = (bf16_t*)(ws + 61122176);    //     16,384 -> end 61,138,560

    const int NB = (N_NODES + 255) / 256;        // 196

    k_split_all<<<544, 256, 0, stream>>>(W0, W1, W2, Wth0, Wtl0, Wth1, Wtl1,
                                         Wth2, Wtl2, cnts, cursor);
    k_hist   <<<(E_TOT + 255) / 256, 256, 0, stream>>>(ei, cnts);
    k_scan1  <<<NB, 256, 0, stream>>>(cnts, offs, bsum);
    k_scan23 <<<NB, 256, 0, stream>>>(offs, bsum, NB);
    k_scatter<<<(E_TOT + 255) / 256, 256, 0, stream>>>(ei, offs, cursor, srcs);

    const int GATHER2_BLOCKS = (N_NODES + 15) / 16;  // 3125 (2 nodes/half-wave)
    const int FINAL_BLOCKS   = (N_NODES + 7) / 8;    // 6250

    // layer 0 (A = x fp32 truncated to bf16 in-register; W0 hi-only in LDS)
    k_gemm256_dual<true><<<DUAL_BLOCKS, 512, 0, stream>>>(x, nullptr, Wth0, as0, ad0, hA_b, As, Ad);
    k_gather256_f<<<GATHER2_BLOCKS, 256, 0, stream>>>(hA_b, As, Ad, offs, cnts, srcs, b0, hB_b);
    // layer 1 (A exact bf16; W1 hi-only in LDS)
    k_gemm256_dual<false><<<DUAL_BLOCKS, 512, 0, stream>>>(nullptr, hB_b, Wth1, as1, ad1, hA_b, As, Ad);
    k_gather256_f<<<GATHER2_BLOCKS, 256, 0, stream>>>(hA_b, As, Ad, offs, cnts, srcs, b1, hB_b);
    // layer 2 (+ fused log_softmax; W2 keeps hi+lo)
    k_gemm32_mfma<<<NB, 256, 0, stream>>>(hB_b, Wth2, Wtl2, as2, ad2, hC, As, Ad);
    k_gather_final_f<<<FINAL_BLOCKS, 256, 0, stream>>>(hC, As, Ad, offs, cnts, srcs, b2, out);
}

// Round 21
// 221.608 us; speedup vs baseline: 1.2453x; 1.2453x over previous
//
#include <hip/hip_runtime.h>
#include <math.h>

#define N_NODES 50000
#define PAD_ROWS 50176                 // 392 * 128
#define DUAL_BLOCKS 196                // each block: tiles b and b+196
#define HALF_OFF (196 * 128)           // 25088 row offset of second half
#define E_RAW   400000
#define E_TOT   (E_RAW + N_NODES)      // 450000 incl. self loops
#define NEG_SLOPE 0.2f

typedef __bf16 bf16_t;
typedef bf16_t bf16x8 __attribute__((ext_vector_type(8)));
typedef bf16_t bf16x4 __attribute__((ext_vector_type(4)));
typedef float  f32x4  __attribute__((ext_vector_type(4)));

__device__ __forceinline__ void gll16(const void* g, void* l) {
    __builtin_amdgcn_global_load_lds(
        (const __attribute__((address_space(1))) void*)g,
        (__attribute__((address_space(3))) void*)l, 16, 0, 0);
}

// ---------------- CSR build ----------------

__global__ void k_hist(const int* __restrict__ ei, int* __restrict__ cnt) {
    int e = blockIdx.x * 256 + threadIdx.x;
    if (e >= E_TOT) return;
    int dst = (e < E_RAW) ? ei[E_RAW + e] : (e - E_RAW);
    atomicAdd(&cnt[dst], 1);
}

__global__ void k_scan1(const int* __restrict__ cnt, int* __restrict__ offs,
                        int* __restrict__ bsum) {
    __shared__ int s[256];
    int i = blockIdx.x * 256 + threadIdx.x;
    int v = (i < N_NODES) ? cnt[i] : 0;
    s[threadIdx.x] = v;
    __syncthreads();
    for (int d = 1; d < 256; d <<= 1) {
        int t = (threadIdx.x >= d) ? s[threadIdx.x - d] : 0;
        __syncthreads();
        s[threadIdx.x] += t;
        __syncthreads();
    }
    if (i < N_NODES) offs[i] = s[threadIdx.x] - v;   // exclusive (intra-block)
    if (threadIdx.x == 255) bsum[blockIdx.x] = s[255];
}

// scan2+scan3 fused (R18-verified)
__global__ void k_scan23(int* __restrict__ offs, const int* __restrict__ bsum,
                         int nb) {
    __shared__ int s[256];
    int v = (threadIdx.x < nb) ? bsum[threadIdx.x] : 0;
    s[threadIdx.x] = v;
    __syncthreads();
    for (int d = 1; d < 256; d <<= 1) {
        int t = (threadIdx.x >= d) ? s[threadIdx.x - d] : 0;
        __syncthreads();
        s[threadIdx.x] += t;
        __syncthreads();
    }
    int add = (blockIdx.x == 0) ? 0 : s[blockIdx.x - 1];
    int i = blockIdx.x * 256 + threadIdx.x;
    if (i < N_NODES) offs[i] += add;
}

__global__ void k_scatter(const int* __restrict__ ei, const int* __restrict__ offs,
                          int* __restrict__ cursor, int* __restrict__ srcs) {
    int e = blockIdx.x * 256 + threadIdx.x;
    if (e < 4) srcs[E_TOT + e] = 0;                 // pad (safe: node 0 valid)
    if (e >= E_TOT) return;
    int src, dst;
    if (e < E_RAW) { src = ei[e]; dst = ei[E_RAW + e]; }
    else           { src = dst = e - E_RAW; }
    int pos = offs[dst] + atomicAdd(&cursor[dst], 1);
    srcs[pos] = src;
}

// ---------------- W splits + cnts/cursor zeroing (runs FIRST) --------------

__global__ void k_split_all(const float* __restrict__ W0, const float* __restrict__ W1,
                            const float* __restrict__ W2,
                            bf16_t* __restrict__ T0h, bf16_t* __restrict__ T0l,
                            bf16_t* __restrict__ T1h, bf16_t* __restrict__ T1l,
                            bf16_t* __restrict__ T2h, bf16_t* __restrict__ T2l,
                            int* __restrict__ cnts, int* __restrict__ cursor) {
    int idx = blockIdx.x * 256 + threadIdx.x;    // 139264 total
    if (idx < N_NODES) { cnts[idx] = 0; cursor[idx] = 0; }
    float v; bf16_t *ph, *pl; int o;
    if (idx < 65536) {
        int k = idx >> 8, n = idx & 255;
        v = W0[idx]; ph = T0h; pl = T0l; o = n * 256 + k;
    } else if (idx < 131072) {
        int i = idx - 65536;
        int k = i >> 8, n = i & 255;
        v = W1[i]; ph = T1h; pl = T1l; o = n * 256 + k;
    } else if (idx < 139264) {
        int i = idx - 131072;                    // < 8192
        int k = i >> 5, n = i & 31;
        v = W2[i]; ph = T2h; pl = T2l; o = n * 256 + k;
    } else return;
    bf16_t h = (bf16_t)v;
    ph[o] = h;
    pl[o] = (bf16_t)(v - (float)h);
}

// ---------------- MFMA GEMM: dual independent tiles per block --------------
// (R13-verified)

template<bool A_FP32>
__global__ __launch_bounds__(512) void k_gemm256_dual(
        const float* __restrict__ Af, const bf16_t* __restrict__ Ab,
        const bf16_t* __restrict__ Bth,
        const float* __restrict__ a_s, const float* __restrict__ a_d,
        bf16_t* __restrict__ Hb, float* __restrict__ As, float* __restrict__ Ad) {
    __shared__ __align__(16) bf16_t Bs[16][8][512];   // 131072 B

    const int tid  = threadIdx.x;
    const int lane = tid & 63;
    const int w    = tid >> 6;       // 0..7: 16-row band
    const int r16  = lane & 15;
    const int kg   = lane >> 4;      // 0..3

    #pragma unroll
    for (int i = 0; i < 16; ++i) {
        int op   = w * 16 + i;       // 0..127
        int nsub = op >> 3;          // 0..15
        int kk   = op & 7;           // 0..7
        gll16(&Bth[(nsub * 16 + r16) * 256 + kk * 32 + kg * 8], &Bs[nsub][kk][0]);
    }

    const int row0  = blockIdx.x * 128 + w * 16 + r16;
    const int row1  = row0 + HALF_OFF;
    const int rowc0 = min(row0, N_NODES - 1);
    const int rowc1 = min(row1, N_NODES - 1);
    const bool ok0  = row0 < N_NODES;
    const bool ok1  = row1 < N_NODES;

    bf16x8 x0[8], x1[8];
    if constexpr (A_FP32) {
        const float* a0 = Af + rowc0 * 256 + kg * 8;
        const float* a1 = Af + rowc1 * 256 + kg * 8;
        #pragma unroll
        for (int kk = 0; kk < 8; ++kk) {
            float4 v0 = *(const float4*)(a0 + kk * 32);
            float4 v1 = *(const float4*)(a0 + kk * 32 + 4);
            float4 u0 = *(const float4*)(a1 + kk * 32);
            float4 u1 = *(const float4*)(a1 + kk * 32 + 4);
            x0[kk] = bf16x8{(bf16_t)v0.x, (bf16_t)v0.y, (bf16_t)v0.z, (bf16_t)v0.w,
                            (bf16_t)v1.x, (bf16_t)v1.y, (bf16_t)v1.z, (bf16_t)v1.w};
            x1[kk] = bf16x8{(bf16_t)u0.x, (bf16_t)u0.y, (bf16_t)u0.z, (bf16_t)u0.w,
                            (bf16_t)u1.x, (bf16_t)u1.y, (bf16_t)u1.z, (bf16_t)u1.w};
        }
    } else {
        const bf16_t* a0 = Ab + rowc0 * 256 + kg * 8;
        const bf16_t* a1 = Ab + rowc1 * 256 + kg * 8;
        #pragma unroll
        for (int kk = 0; kk < 8; ++kk) {
            x0[kk] = *(const bf16x8*)(a0 + kk * 32);
            x1[kk] = *(const bf16x8*)(a1 + kk * 32);
        }
    }
    __syncthreads();   // B resident

    f32x4 acc0[16] = {}, acc1[16] = {};
    #pragma unroll
    for (int kk = 0; kk < 8; ++kk) {
        #pragma unroll
        for (int n = 0; n < 16; ++n) {
            bf16x8 wf = *(const bf16x8*)&Bs[n][kk][lane * 8];
            acc0[n] = __builtin_amdgcn_mfma_f32_16x16x32_bf16(wf, x0[kk], acc0[n], 0, 0, 0);
            acc1[n] = __builtin_amdgcn_mfma_f32_16x16x32_bf16(wf, x1[kk], acc1[n], 0, 0, 0);
        }
    }

    {
        float ss = 0.f, sd = 0.f;
        #pragma unroll
        for (int n = 0; n < 16; ++n) {
            f32x4 v = acc0[n];
            if (ok0) {
                bf16x4 st = {(bf16_t)v[0], (bf16_t)v[1], (bf16_t)v[2], (bf16_t)v[3]};
                *(bf16x4*)&Hb[row0 * 256 + n * 16 + kg * 4] = st;
            }
            float4 a4 = *(const float4*)&a_s[n * 16 + kg * 4];
            float4 d4 = *(const float4*)&a_d[n * 16 + kg * 4];
            ss += v[0] * a4.x + v[1] * a4.y + v[2] * a4.z + v[3] * a4.w;
            sd += v[0] * d4.x + v[1] * d4.y + v[2] * d4.z + v[3] * d4.w;
        }
        ss += __shfl_xor(ss, 16); ss += __shfl_xor(ss, 32);
        sd += __shfl_xor(sd, 16); sd += __shfl_xor(sd, 32);
        if (ok0 && kg == 0) { As[row0] = ss; Ad[row0] = sd; }
    }
    {
        float ss = 0.f, sd = 0.f;
        #pragma unroll
        for (int n = 0; n < 16; ++n) {
            f32x4 v = acc1[n];
            if (ok1) {
                bf16x4 st = {(bf16_t)v[0], (bf16_t)v[1], (bf16_t)v[2], (bf16_t)v[3]};
                *(bf16x4*)&Hb[row1 * 256 + n * 16 + kg * 4] = st;
            }
            float4 a4 = *(const float4*)&a_s[n * 16 + kg * 4];
            float4 d4 = *(const float4*)&a_d[n * 16 + kg * 4];
            ss += v[0] * a4.x + v[1] * a4.y + v[2] * a4.z + v[3] * a4.w;
            sd += v[0] * d4.x + v[1] * d4.y + v[2] * d4.z + v[3] * d4.w;
        }
        ss += __shfl_xor(ss, 16); ss += __shfl_xor(ss, 32);
        sd += __shfl_xor(sd, 16); sd += __shfl_xor(sd, 32);
        if (ok1 && kg == 0) { As[row1] = ss; Ad[row1] = sd; }
    }
}

// ---------------- GEMM 32-out (layer 2), swapped operands ------------------

__global__ __launch_bounds__(256) void k_gemm32_mfma(
        const bf16_t* __restrict__ Ab,
        const bf16_t* __restrict__ Bth, const bf16_t* __restrict__ Btl,
        const float* __restrict__ a_s, const float* __restrict__ a_d,
        float* __restrict__ Hc, float* __restrict__ As, float* __restrict__ Ad) {
    const int tid  = threadIdx.x;
    const int lane = tid & 63;
    const int wv   = tid >> 6;
    const int r16  = lane & 15;
    const int kg   = lane >> 4;
    const int rowg = blockIdx.x * 256 + wv * 64;

    int aoff[4], boff[2];
    #pragma unroll
    for (int m = 0; m < 4; ++m) {
        int row = rowg + m * 16 + r16;
        if (row >= N_NODES) row = N_NODES - 1;
        aoff[m] = row * 256 + kg * 8;
    }
    #pragma unroll
    for (int n = 0; n < 2; ++n)
        boff[n] = (n * 16 + r16) * 256 + kg * 8;

    f32x4 accT[2][4] = {};   // [n][m]

    #pragma unroll
    for (int kk = 0; kk < 8; ++kk) {
        const int k0 = kk * 32;
        bf16x8 ah[4], bh[2], bl[2];
        #pragma unroll
        for (int m = 0; m < 4; ++m)
            ah[m] = *(const bf16x8*)(Ab + aoff[m] + k0);
        #pragma unroll
        for (int n = 0; n < 2; ++n) {
            bh[n] = *(const bf16x8*)(Bth + boff[n] + k0);
            bl[n] = *(const bf16x8*)(Btl + boff[n] + k0);
        }
        #pragma unroll
        for (int n = 0; n < 2; ++n) {
            #pragma unroll
            for (int m = 0; m < 4; ++m) {
                accT[n][m] = __builtin_amdgcn_mfma_f32_16x16x32_bf16(bh[n], ah[m], accT[n][m], 0, 0, 0);
                accT[n][m] = __builtin_amdgcn_mfma_f32_16x16x32_bf16(bl[n], ah[m], accT[n][m], 0, 0, 0);
            }
        }
    }

    float4 as4[2], ad4[2];
    #pragma unroll
    for (int n = 0; n < 2; ++n) {
        as4[n] = *(const float4*)&a_s[n * 16 + kg * 4];
        ad4[n] = *(const float4*)&a_d[n * 16 + kg * 4];
    }
    #pragma unroll
    for (int m = 0; m < 4; ++m) {
        int row = rowg + m * 16 + r16;
        bool ok = row < N_NODES;
        float ss = 0.f, sd = 0.f;
        #pragma unroll
        for (int n = 0; n < 2; ++n) {
            f32x4 v = accT[n][m];
            if (ok) {
                float4 st = {v[0], v[1], v[2], v[3]};
                *(float4*)&Hc[row * 32 + n * 16 + kg * 4] = st;
            }
            ss += v[0] * as4[n].x + v[1] * as4[n].y + v[2] * as4[n].z + v[3] * as4[n].w;
            sd += v[0] * ad4[n].x + v[1] * ad4[n].y + v[2] * ad4[n].z + v[3] * ad4[n].w;
        }
        ss += __shfl_xor(ss, 16); ss += __shfl_xor(ss, 32);
        sd += __shfl_xor(sd, 16); sd += __shfl_xor(sd, 32);
        if (ok && kg == 0) { As[row] = ss; Ad[row] = sd; }
    }
}

// ---------------- Fused softmax+gather (256-wide), max-free ----------------
// (R18-verified: best measured configuration)

__global__ __launch_bounds__(256) void k_gather256_f(
        const bf16_t* __restrict__ Hb,
        const float* __restrict__ As0, const float* __restrict__ Ad0,
        const float* __restrict__ As1, const float* __restrict__ Ad1,
        const int dual,
        const int* __restrict__ offs, const int* __restrict__ cnts,
        const int* __restrict__ srcs,
        const float* __restrict__ bias, bf16_t* __restrict__ Hout) {
    const int gl   = threadIdx.x & 31;
    const int node = blockIdx.x * 8 + (threadIdx.x >> 5);
    if (node >= N_NODES) return;
    const int start = offs[node];
    const int cnt   = cnts[node];
    float ad = Ad0[node];
    if (dual) ad += Ad1[node];
    const int c0 = gl * 8;

    float acc[8] = {};
    float denom = 0.f;
    for (int j = 0; j < cnt; j += 4) {
        int s4[4];
        #pragma unroll
        for (int k = 0; k < 4; ++k) s4[k] = srcs[start + j + k];  // pad-safe
        #pragma unroll
        for (int k = 0; k < 4; ++k) {
            int s = s4[k];
            float as = As0[s];
            if (dual) as += As1[s];
            float e = as + ad;
            e = e > 0.f ? e : NEG_SLOPE * e;
            float p = (j + k < cnt) ? __expf(e) : 0.f;
            denom += p;
            bf16x8 hv = *(const bf16x8*)&Hb[s * 256 + c0];
            #pragma unroll
            for (int q = 0; q < 8; ++q) acc[q] += p * (float)hv[q];
        }
    }
    const float iv = 1.f / denom;

    float4 b0 = *(const float4*)&bias[c0];
    float4 b1 = *(const float4*)&bias[c0 + 4];
    float bb[8] = {b0.x, b0.y, b0.z, b0.w, b1.x, b1.y, b1.z, b1.w};
    bf16x8 st;
    #pragma unroll
    for (int q = 0; q < 8; ++q) {
        float v = acc[q] * iv + bb[q];
        v = v / (1.f + __expf(-v));
        st[q] = (bf16_t)v;
    }
    *(bf16x8*)&Hout[node * 256 + c0] = st;
}

// ---------------- Fused final gather (max-free) + bias + log_softmax -------

__global__ __launch_bounds__(256) void k_gather_final_f(
        const float* __restrict__ Hc,   // [N][32]
        const float* __restrict__ As0, const float* __restrict__ Ad0,
        const int* __restrict__ offs, const int* __restrict__ cnts,
        const int* __restrict__ srcs,
        const float* __restrict__ bias, float* __restrict__ out) {
    const int gl   = threadIdx.x & 31;
    const int node = blockIdx.x * 8 + (threadIdx.x >> 5);
    if (node >= N_NODES) return;
    const int start = offs[node];
    const int cnt   = cnts[node];
    const float ad  = Ad0[node];

    float acc = 0.f, denom = 0.f;
    for (int j = 0; j < cnt; j += 4) {
        int s4[4];
        #pragma unroll
        for (int k = 0; k < 4; ++k) s4[k] = srcs[start + j + k];
        #pragma unroll
        for (int k = 0; k < 4; ++k) {
            int s = s4[k];
            float e = As0[s] + ad;
            e = e > 0.f ? e : NEG_SLOPE * e;
            float p = (j + k < cnt) ? __expf(e) : 0.f;
            denom += p;
            acc += p * Hc[s * 32 + gl];
        }
    }

    float v = acc / denom + bias[gl];
    float mm = v;
    #pragma unroll
    for (int o = 16; o; o >>= 1) mm = fmaxf(mm, __shfl_xor(mm, o));
    float ex = __expf(v - mm), sum = ex;
    #pragma unroll
    for (int o = 16; o; o >>= 1) sum += __shfl_xor(sum, o);
    out[node * 32 + gl] = v - mm - __logf(sum);
}

// ---------------- launch ----------------

extern "C" void kernel_launch(void* const* d_in, const int* in_sizes, int n_in,
                              void* d_out, int out_size, void* d_ws, size_t ws_size,
                              hipStream_t stream) {
    const float* x   = (const float*)d_in[0];
    const int*   ei  = (const int*)  d_in[1];
    const float* W0  = (const float*)d_in[2];
    const float* as0 = (const float*)d_in[3];
    const float* ad0 = (const float*)d_in[4];
    const float* b0  = (const float*)d_in[5];
    const float* W1  = (const float*)d_in[6];
    const float* as1 = (const float*)d_in[7];
    const float* ad1 = (const float*)d_in[8];
    const float* b1  = (const float*)d_in[9];
    const float* W2  = (const float*)d_in[10];
    const float* as2 = (const float*)d_in[11];
    const float* ad2 = (const float*)d_in[12];
    const float* b2  = (const float*)d_in[13];
    float* out = (float*)d_out;

    char* ws = (char*)d_ws;
    bf16_t* hA_b  = (bf16_t*)(ws + 0);           // 25,690,112
    bf16_t* hB_b  = (bf16_t*)(ws + 25690112);    // 25,690,112
    float*  hC    = (float*) (ws + 51380224);    //  6,400,000
    float*  As    = (float*) (ws + 57780224);    //    200,000
    float*  Ad    = (float*) (ws + 57980224);    //    200,000
    int*    cnts  = (int*)   (ws + 58380224);
    int*    cursor= (int*)   (ws + 58580224);
    int*    offs  = (int*)   (ws + 58780224);
    int*    srcs  = (int*)   (ws + 58980224);    //  1,800,016 (E_TOT+4)
    int*    bsum  = (int*)   (ws + 60780240);    //      1,024
    bf16_t* Wth0  = (bf16_t*)(ws + 60781312);    //    131,072
    bf16_t* Wtl0  = (bf16_t*)(ws + 60912384);    //    131,072
    bf16_t* Wth1  = (bf16_t*)(ws + 61043456);    //    131,072
    bf16_t* Wtl1  = (bf16_t*)(ws + 61174528);    //    131,072
    bf16_t* Wth2  = (bf16_t*)(ws + 61305600);    //     16,384
    bf16_t* Wtl2  = (bf16_t*)(ws + 61321984);    //     16,384
    float*  As1p  = (float*) (ws + 61338368);    //    200,000 (layer-1 partials)
    float*  Ad1p  = (float*) (ws + 61538368);    //    200,000 -> end 61,738,368

    const int NB = (N_NODES + 255) / 256;        // 196

    // split_all runs first and zeroes cnts/cursor
    k_split_all<<<544, 256, 0, stream>>>(W0, W1, W2, Wth0, Wtl0, Wth1, Wtl1,
                                         Wth2, Wtl2, cnts, cursor);
    k_hist   <<<(E_TOT + 255) / 256, 256, 0, stream>>>(ei, cnts);
    k_scan1  <<<NB, 256, 0, stream>>>(cnts, offs, bsum);
    k_scan23 <<<NB, 256, 0, stream>>>(offs, bsum, NB);
    k_scatter<<<(E_TOT + 255) / 256, 256, 0, stream>>>(ei, offs, cursor, srcs);

    const int GATHER_BLOCKS = (N_NODES + 7) / 8;   // 6250

    // layer 0 (A = x fp32 truncated to bf16 in-register; W0 hi-only in LDS)
    k_gemm256_dual<true><<<DUAL_BLOCKS, 512, 0, stream>>>(x, nullptr, Wth0, as0, ad0, hA_b, As, Ad);
    k_gather256_f<<<GATHER_BLOCKS, 256, 0, stream>>>(hA_b, As, Ad, As, Ad, 0, offs, cnts, srcs, b0, hB_b);
    // layer 1 (A exact bf16; W1 hi-only in LDS)
    k_gemm256_dual<false><<<DUAL_BLOCKS, 512, 0, stream>>>(nullptr, hB_b, Wth1, as1, ad1, hA_b, As, Ad);
    k_gather256_f<<<GATHER_BLOCKS, 256, 0, stream>>>(hA_b, As, Ad, As, Ad, 0, offs, cnts, srcs, b1, hB_b);
    // layer 2 (+ fused log_softmax; W2 keeps hi+lo)
    k_gemm32_mfma<<<NB, 256, 0, stream>>>(hB_b, Wth2, Wtl2, as2, ad2, hC, As, Ad);
    k_gather_final_f<<<GATHER_BLOCKS, 256, 0, stream>>>(hC, As, Ad, offs, cnts, srcs, b2, out);
}